// Round 7
// baseline (138.758 us; speedup 1.0000x reference)
//
#include <hip/hip_runtime.h>
#include <math.h>

// DirectionalContrastiveLoss — N=8, C=192, H=W=112, T=0.1
//
// R12: HBM-steady-state polish of the proven R7/R8/R10 structure.
//  Model (units fixed): VALU ~1.1us, LDS ~5.5us, HBM = 77MB x halo ~16-17us
//  -> dcl_main is HBM-bound; occupancy/barrier/XCD attacks were nulls
//  because staging bandwidth dominates (12 chunks x ~3400cyc/CU).
//  - tile 14x14 (halo 16x16 = 256 slots = 1 slot/thread exactly, no EXTRA
//    branch): halo 1.38 -> 1.306; grid (8,8,8) = 512 blocks = 2/CU.
//  - NT=512, two 256-thread channel-halves; KCH=8 double-buffered,
//    12 barriers (proven); pair-blocking 2px/thread (98 pairs/half,
//    rows 2p,2p+1 — 14 rows even, no duplicate-row hack), ~100 VGPR.
//  - rows padded to 17 v4f (2-way banks only).
//  - dcl_final FUSED: per-block atomicAdd(double) + device counter; last
//    block writes out[0]. Saves one dispatch + launch gap.

namespace {
constexpr int N_ = 8, C_ = 192, H_ = 112, W_ = 112;
constexpr int HW = H_ * W_;
constexpr int TH = 14, WS = 14;        // pixel tile
constexpr int TCOLS = 16;              // halo cols (rows = 16)
constexpr int TPAD = 17;               // padded row stride (v4f units)
constexpr int TILE_E = 256;            // 16x16 halo slots = NT2
constexpr int NT2 = 256;               // threads per channel-half
constexpr int NT = 2 * NT2;            // 512
constexpr int NPR = 7 * WS;            // 98 pair threads per half
constexpr int CHALF = C_ / 2;          // 96
constexpr int KCH = 8;                 // channels per chunk per half
constexpr int GRP = KCH / 4;           // 2 float4 groups
constexpr int NCHUNK = CHALF / KCH;    // 12
constexpr int NBLK = 8 * 8 * 8;        // 512
constexpr float INV_T = 10.0f;
constexpr double TOTAL = (double)N_ * N_ * H_ * W_;  // 802816
}

typedef float v2f __attribute__((ext_vector_type(2)));
typedef float v4f __attribute__((ext_vector_type(4)));

__device__ __forceinline__ void pk(v2f& a, v2f x, v2f y) {
    asm("v_pk_fma_f32 %0, %1, %2, %0" : "+v"(a) : "v"(x), "v"(y));
}
__device__ __forceinline__ void pk4(v2f& a, v4f x, v4f y) {
    pk(a, x.lo, y.lo); pk(a, x.hi, y.hi);
}

__device__ __forceinline__ float sel3(int d, float a, float b, float c) {
    float r = (d < 0) ? a : b;
    return (d > 0) ? c : r;
}

extern "C" __global__ void __launch_bounds__(NT, 4)
dcl_main(const float* __restrict__ feat,
         const int* __restrict__ labels,
         const int* __restrict__ dirs,
         double* __restrict__ acc,         // d_ws: [double sum][uint counter]
         float* __restrict__ out)
{
    __shared__ v4f   tiles[2][2][GRP][16 * TPAD];  // 34.8 KB
    __shared__ float ssp[2][TILE_E];               // 2 KB
    __shared__ float ssbuf[TILE_E];                // 1 KB
    __shared__ float exA[NPR][9];                  // half1's px0 partials
    __shared__ float exB[NPR][9];                  // half0's px1 partials
    __shared__ float red[NT / 64];

    const int gx0 = blockIdx.x * WS;
    const int gy0 = blockIdx.y * TH;
    const int n   = blockIdx.z;

    const int tid  = threadIdx.x;
    const int half = tid >> 8;
    const int t8   = tid & (NT2 - 1);

    // ---- staging: exactly one slot per thread
    const int sr = t8 >> 4, sc = t8 & 15;
    const int spad = sr * TPAD + sc;
    const int gofs = min(max(gy0 + sr - 1, 0), H_ - 1) * W_
                   + min(max(gx0 + sc - 1, 0), W_ - 1);

    // ---- pair mapping: rows (2pr, 2pr+1), col tx
    const bool is_p = (t8 < NPR);
    const int pr = t8 / WS;               // 0..6
    const int tx = t8 - pr * WS;          // 0..13
    const int top = (2 * pr) * TPAD + tx; // window upper-left (v4f idx)
    const int gj  = gx0 + tx;

    const float* __restrict__ plane =
        feat + ((size_t)n * C_ + (size_t)half * CHALF) * HW;

    float ss0 = 0.0f;

    // ---- prologue: stage chunk 0 into buffer 0
    {
        #pragma unroll
        for (int g = 0; g < GRP; ++g) {
            float a0 = plane[(size_t)(4 * g + 0) * HW + gofs];
            float a1 = plane[(size_t)(4 * g + 1) * HW + gofs];
            float a2 = plane[(size_t)(4 * g + 2) * HW + gofs];
            float a3 = plane[(size_t)(4 * g + 3) * HW + gofs];
            ss0 += a0 * a0 + a1 * a1 + a2 * a2 + a3 * a3;
            v4f v = {a0, a1, a2, a3};
            tiles[half][0][g][spad] = v;
        }
    }
    __syncthreads();

    // accumulators: 15 v2f. q0 = px0's 7 own dirs, q1 = px1's, s01 shared
    // q0: [0]=(-1,-1) [1]=(-1,0) [2]=(-1,1) [3]=(0,-1) [4]=(0,1) [5]=(1,-1) [6]=(1,1)
    // q1: [0]=(-1,-1) [1]=(-1,1) [2]=(0,-1) [3]=(0,1) [4]=(1,-1) [5]=(1,0) [6]=(1,1)
    v2f q0[7], q1[7], s01;
    {
        const v2f z = {0.f, 0.f};
        #pragma unroll
        for (int d = 0; d < 7; ++d) { q0[d] = z; q1[d] = z; }
        s01 = z;
    }

    // ---- chunk loop: 1 barrier per 8 channels per half, double-buffered
    for (int t = 0; t < NCHUNK; ++t) {
        float pv[KCH];
        const bool more = (t + 1 < NCHUNK);
        if (more) {
            const float* p = plane + (size_t)(t + 1) * KCH * HW;
            #pragma unroll
            for (int k = 0; k < KCH; ++k) pv[k] = p[(size_t)k * HW + gofs];
        }

        if (is_p) {
            #pragma unroll
            for (int g = 0; g < GRP; ++g) {
                const v4f* __restrict__ cp = tiles[half][t & 1][g];
                v4f A0 = cp[top +  0], B0 = cp[top +  1], C0 = cp[top +  2];
                v4f A1 = cp[top + 17], B1 = cp[top + 18], C1 = cp[top + 19];
                v4f A2 = cp[top + 34], B2 = cp[top + 35], C2 = cp[top + 36];
                // px0 (center B1; slot rows 2pr..2pr+2)
                pk4(q0[0], B1, A0); pk4(q0[1], B1, B0); pk4(q0[2], B1, C0);
                pk4(q0[3], B1, A1); pk4(q0[4], B1, C1);
                pk4(q0[5], B1, A2); pk4(s01,   B1, B2); pk4(q0[6], B1, C2);
                v4f A3 = cp[top + 51], B3 = cp[top + 52], C3 = cp[top + 53];
                // px1 (center B2; slot rows 2pr+1..2pr+3); (-1,0) = s01
                pk4(q1[0], B2, A1); pk4(q1[1], B2, C1);
                pk4(q1[2], B2, A2); pk4(q1[3], B2, C2);
                pk4(q1[4], B2, A3); pk4(q1[5], B2, B3); pk4(q1[6], B2, C3);
            }
        }

        if (more) {
            const int nb = (t + 1) & 1;
            #pragma unroll
            for (int g = 0; g < GRP; ++g) {
                float a0 = pv[4 * g + 0], a1 = pv[4 * g + 1];
                float a2 = pv[4 * g + 2], a3 = pv[4 * g + 3];
                ss0 += a0 * a0 + a1 * a1 + a2 * a2 + a3 * a3;
                v4f v = {a0, a1, a2, a3};
                tiles[half][nb][g][spad] = v;
            }
            __syncthreads();
        }
    }

    // ---- publish norm partials + cross-half dot partials
    ssp[half][t8] = ss0;
    if (is_p) {
        if (half == 1) {   // send px0 partials (order 00,01,02,10,12,20,21,22)
            float* d = exA[t8];
            d[0]=q0[0].x+q0[0].y; d[1]=q0[1].x+q0[1].y; d[2]=q0[2].x+q0[2].y;
            d[3]=q0[3].x+q0[3].y; d[4]=q0[4].x+q0[4].y; d[5]=q0[5].x+q0[5].y;
            d[6]=s01.x+s01.y;     d[7]=q0[6].x+q0[6].y;
        } else {           // send px1 partials
            float* d = exB[t8];
            d[0]=q1[0].x+q1[0].y; d[1]=s01.x+s01.y;     d[2]=q1[1].x+q1[1].y;
            d[3]=q1[2].x+q1[2].y; d[4]=q1[3].x+q1[3].y; d[5]=q1[4].x+q1[4].y;
            d[6]=q1[5].x+q1[5].y; d[7]=q1[6].x+q1[6].y;
        }
    }
    __syncthreads();
    if (tid < TILE_E)
        ssbuf[tid] = 1.0f / fmaxf(sqrtf(ssp[0][tid] + ssp[1][tid]), 1e-12f);
    __syncthreads();

    float lp = 0.0f;
    if (is_p) {
        auto epi = [&](const float* s8, int ciu, int gi) -> float {
            const float ssq = ssp[0][ciu] + ssp[1][ciu];
            const float invc = ssbuf[ciu] * INV_T;
            const float l00 = s8[0] * invc * ssbuf[ciu - TCOLS - 1];
            const float l01 = s8[1] * invc * ssbuf[ciu - TCOLS];
            const float l02 = s8[2] * invc * ssbuf[ciu - TCOLS + 1];
            const float l10 = s8[3] * invc * ssbuf[ciu - 1];
            const float l11 = ssq  * invc * ssbuf[ciu];
            const float l12 = s8[4] * invc * ssbuf[ciu + 1];
            const float l20 = s8[5] * invc * ssbuf[ciu + TCOLS - 1];
            const float l21 = s8[6] * invc * ssbuf[ciu + TCOLS];
            const float l22 = s8[7] * invc * ssbuf[ciu + TCOLS + 1];

            const int pix = gi * W_ + gj;
            float denom = 0.f, sumlog = 0.f;
            #pragma unroll
            for (int m = 0; m < N_; ++m) {
                int d0 = dirs[((m * 2 + 0) * H_ + gi) * W_ + gj];
                int d1 = dirs[((m * 2 + 1) * H_ + gi) * W_ + gj];
                float e0 = sel3(d1, l00, l01, l02);
                float e1 = sel3(d1, l10, l11, l12);
                float e2 = sel3(d1, l20, l21, l22);
                float lm = sel3(d0, e0, e1, e2);
                int labm = labels[m * HW + pix];
                int labn = labels[n * HW + (gi + d0) * W_ + (gj + d1)];
                bool msk = (labm == labn);
                float e = msk ? __expf(lm) : 0.f;
                denom += e;
                sumlog += msk ? lm : -INFINITY;
            }
            return 8.0f * __logf(denom + 1e-6f) - sumlog;
        };

        if (half == 0) {   // own px0 (even rows): combine with half1's exA
            float f[8];
            const float* e = exA[t8];
            f[0]=q0[0].x+q0[0].y+e[0]; f[1]=q0[1].x+q0[1].y+e[1];
            f[2]=q0[2].x+q0[2].y+e[2]; f[3]=q0[3].x+q0[3].y+e[3];
            f[4]=q0[4].x+q0[4].y+e[4]; f[5]=q0[5].x+q0[5].y+e[5];
            f[6]=s01.x+s01.y+e[6];     f[7]=q0[6].x+q0[6].y+e[7];
            lp = epi(f, (2 * pr + 1) * TCOLS + tx + 1, gy0 + 2 * pr);
        } else {           // own px1 (odd rows): combine with half0's exB
            float f[8];
            const float* e = exB[t8];
            f[0]=q1[0].x+q1[0].y+e[0]; f[1]=s01.x+s01.y+e[1];
            f[2]=q1[1].x+q1[1].y+e[2]; f[3]=q1[2].x+q1[2].y+e[3];
            f[4]=q1[3].x+q1[3].y+e[4]; f[5]=q1[4].x+q1[4].y+e[5];
            f[6]=q1[5].x+q1[5].y+e[6]; f[7]=q1[6].x+q1[6].y+e[7];
            lp = epi(f, (2 * pr + 2) * TCOLS + tx + 1, gy0 + 2 * pr + 1);
        }
    }

    // ---- block reduction (8 waves) + fused device-wide finalize
    #pragma unroll
    for (int off = 32; off > 0; off >>= 1) lp += __shfl_down(lp, off, 64);
    const int wave = tid >> 6, lane = tid & 63;
    if (lane == 0) red[wave] = lp;
    __syncthreads();
    if (tid == 0) {
        float tsum = 0.f;
        #pragma unroll
        for (int w = 0; w < NT / 64; ++w) tsum += red[w];
        atomicAdd(acc, (double)tsum);          // device-scope (m20)
        __threadfence();                        // release
        unsigned* ctr = (unsigned*)(acc + 1);
        unsigned old = atomicAdd(ctr, 1u);
        if (old == (unsigned)(NBLK - 1)) {     // last block
            __threadfence();                    // acquire
            double s = atomicAdd(acc, 0.0);     // coherent read
            out[0] = (float)(s / TOTAL);
        }
    }
}

extern "C" void kernel_launch(void* const* d_in, const int* in_sizes, int n_in,
                              void* d_out, int out_size, void* d_ws, size_t ws_size,
                              hipStream_t stream) {
    const float* feat   = (const float*)d_in[0];
    const int*   labels = (const int*)d_in[1];
    const int*   dirs   = (const int*)d_in[2];
    double* acc = (double*)d_ws;
    float*  out = (float*)d_out;

    hipMemsetAsync(acc, 0, 16, stream);        // zero sum + counter
    dim3 grid(W_ / WS, H_ / TH, N_);           // (8, 8, 8) = 512 blocks
    dcl_main<<<grid, NT, 0, stream>>>(feat, labels, dirs, acc, out);
}

// Round 8
// 123.133 us; speedup vs baseline: 1.1269x; 1.1269x over previous
//
#include <hip/hip_runtime.h>
#include <math.h>

// DirectionalContrastiveLoss — N=8, C=192, H=W=112, T=0.1
//
// R13 = R10 (proven structure, kernel ~24.6us) + staging-latency removal.
//  Model (from R12's measured counters, fits all rounds): per chunk each
//  block streams 17.3KB; 2 blk/CU -> 3460cyc/chunk, x12 = 17.3us pure HBM
//  stream; the 22-25us plateau = that stream at ~70% efficiency. The ~7us
//  gap is load-latency exposed at the 12 vmcnt(0)-draining __syncthreads.
//  Fix (one mechanism, two mechanics):
//   1. main-loop barrier = s_waitcnt lgkmcnt(0) + raw s_barrier (writer-side
//      LDS handoff, HK pattern) — register-dest global loads stay in flight.
//   2. 2-deep prefetch: chunk t+2 issued during compute(t); ping-pong
//      pvA/pvB statically unrolled x2 (no runtime-indexed reg arrays).
//  Geometry/compute identical to R10: tile 7x28 (halo 9x30), 512 blocks,
//  NT=512 two channel-halves, KCH=8, pair-blocking, XCD swizzle, separate
//  dcl_final. VGPR ~76 < 128 cap of launch_bounds(512,4).

namespace {
constexpr int N_ = 8, C_ = 192, H_ = 112, W_ = 112;
constexpr int HW = H_ * W_;
constexpr int TH = 7, WS = 28;         // pixel tile
constexpr int TROWS = 9, TCOLS = 30;   // +halo
constexpr int SPAD = 31;               // padded row stride (v4f units)
constexpr int TILE_E = TROWS * TCOLS;  // 270 staging slots
constexpr int NT2 = 256;               // threads per channel-half
constexpr int NT = 2 * NT2;            // 512
constexpr int EXTRA = TILE_E - NT2;    // 14 threads own a 2nd slot
constexpr int NPR = 4 * WS;            // 112 pair threads per half
constexpr int CHALF = C_ / 2;          // 96
constexpr int KCH = 8;                 // channels per chunk per half
constexpr int GRP = KCH / 4;           // 2 float4 groups
constexpr int NCHUNK = CHALF / KCH;    // 12 (even — required by x2 unroll)
constexpr int NBLK = (W_ / WS) * (H_ / TH) * N_;  // 4*16*8 = 512
constexpr float INV_T = 10.0f;
constexpr double TOTAL = (double)N_ * N_ * H_ * W_;  // 802816
}

typedef float v2f __attribute__((ext_vector_type(2)));
typedef float v4f __attribute__((ext_vector_type(4)));

__device__ __forceinline__ void pk(v2f& a, v2f x, v2f y) {
    asm("v_pk_fma_f32 %0, %1, %2, %0" : "+v"(a) : "v"(x), "v"(y));
}
__device__ __forceinline__ void pk4(v2f& a, v4f x, v4f y) {
    pk(a, x.lo, y.lo); pk(a, x.hi, y.hi);
}

__device__ __forceinline__ float sel3(int d, float a, float b, float c) {
    float r = (d < 0) ? a : b;
    return (d > 0) ? c : r;
}

// Writer-side LDS handoff barrier that does NOT drain vmcnt:
// ds_writes retired (lgkmcnt 0) -> s_barrier. Global loads to registers
// stay in flight; their consumers get compiler-inserted vmcnt waits.
#define BAR() do {                                            \
    asm volatile("s_waitcnt lgkmcnt(0)" ::: "memory");        \
    __builtin_amdgcn_sched_barrier(0);                        \
    __builtin_amdgcn_s_barrier();                             \
    __builtin_amdgcn_sched_barrier(0);                        \
} while (0)

extern "C" __global__ void __launch_bounds__(NT, 4)
dcl_main(const float* __restrict__ feat,
         const int* __restrict__ labels,
         const int* __restrict__ dirs,
         double* __restrict__ partial, int use_partial)
{
    __shared__ v4f   tiles[2][2][GRP][TROWS * SPAD];  // 34.9 KB
    __shared__ float ssp[2][TILE_E];                  // 2.16 KB
    __shared__ float ssbuf[TILE_E];                   // 1.08 KB
    __shared__ float exA[NPR][9];                     // half1's px0 partials
    __shared__ float exB[NPR][9];                     // half0's px1 partials
    __shared__ float red[NT / 64];

    const int bid = blockIdx.x;
    const int n   = bid & 7;            // XCD swizzle: image n -> XCD n
    const int tt_ = bid >> 3;           // 0..63
    const int tyb = tt_ >> 2;           // 0..15
    const int txb = tt_ & 3;            // 0..3
    const int gy0 = tyb * TH;
    const int gx0 = txb * WS;

    const int tid  = threadIdx.x;
    const int half = tid >> 8;
    const int t8   = tid & (NT2 - 1);

    // ---- staging slots -> clamped global offsets + padded LDS index
    int gofs0, gofs1 = 0, spad0, spad1 = 0;
    {
        int sr = t8 / TCOLS, sc = t8 - sr * TCOLS;
        spad0 = sr * SPAD + sc;
        gofs0 = min(max(gy0 + sr - 1, 0), H_ - 1) * W_
              + min(max(gx0 + sc - 1, 0), W_ - 1);
        if (t8 < EXTRA) {
            int s2 = t8 + NT2;
            sr = s2 / TCOLS; sc = s2 - sr * TCOLS;
            spad1 = sr * SPAD + sc;
            gofs1 = min(max(gy0 + sr - 1, 0), H_ - 1) * W_
                  + min(max(gx0 + sc - 1, 0), W_ - 1);
        }
    }

    // ---- pair mapping
    const bool is_p = (t8 < NPR);
    const int pr = t8 / WS;               // 0..3
    const int tx = t8 - pr * WS;          // 0..27
    const int r0 = (pr == 3) ? 5 : 2 * pr;   // px0 image row in tile
    const bool px0v = (pr < 3);              // pr3's px0 (row 5) is a dup
    const int top = r0 * SPAD + tx;       // window upper-left (v4f idx)
    const int gj  = gx0 + tx;

    const float* __restrict__ plane =
        feat + ((size_t)n * C_ + (size_t)half * CHALF) * HW;

    float ss0 = 0.0f, ss1 = 0.0f;

    // accumulators: 15 v2f (q0 = px0's 7 dirs, q1 = px1's 7, s01 shared)
    v2f q0[7], q1[7], s01;
    {
        const v2f z = {0.f, 0.f};
        #pragma unroll
        for (int d = 0; d < 7; ++d) { q0[d] = z; q1[d] = z; }
        s01 = z;
    }

    // ---- prefetch registers (2-deep, ping-pong)
    float pvA0[KCH], pvA1[KCH], pvB0[KCH], pvB1[KCH];

    auto writebuf = [&](int nb, const float (&h0)[KCH], const float (&h1)[KCH]) {
        #pragma unroll
        for (int g = 0; g < GRP; ++g) {
            float a0 = h0[4*g+0], a1 = h0[4*g+1], a2 = h0[4*g+2], a3 = h0[4*g+3];
            ss0 += a0*a0 + a1*a1 + a2*a2 + a3*a3;
            v4f v = {a0, a1, a2, a3};
            tiles[half][nb][g][spad0] = v;
        }
        if (t8 < EXTRA) {
            #pragma unroll
            for (int g = 0; g < GRP; ++g) {
                float a0 = h1[4*g+0], a1 = h1[4*g+1], a2 = h1[4*g+2], a3 = h1[4*g+3];
                ss1 += a0*a0 + a1*a1 + a2*a2 + a3*a3;
                v4f v = {a0, a1, a2, a3};
                tiles[half][nb][g][spad1] = v;
            }
        }
    };
    auto loadch = [&](int c, float (&f0)[KCH], float (&f1)[KCH]) {
        const float* p = plane + (size_t)c * KCH * HW;
        #pragma unroll
        for (int k = 0; k < KCH; ++k) f0[k] = p[(size_t)k * HW + gofs0];
        if (t8 < EXTRA) {
            #pragma unroll
            for (int k = 0; k < KCH; ++k) f1[k] = p[(size_t)k * HW + gofs1];
        }
    };

    // ---- prologue: chunk0 -> pvB (write to buf0), chunk1 -> pvA (hold)
    loadch(0, pvB0, pvB1);
    loadch(1, pvA0, pvA1);
    writebuf(0, pvB0, pvB1);
    BAR();

    auto step = [&](int t, float (&h0)[KCH], float (&h1)[KCH],
                           float (&f0)[KCH], float (&f1)[KCH]) {
        if (t + 2 < NCHUNK) loadch(t + 2, f0, f1);   // fill other set

        if (is_p) {
            #pragma unroll
            for (int g = 0; g < GRP; ++g) {
                const v4f* __restrict__ cp = tiles[half][t & 1][g];
                v4f A0 = cp[top +  0], B0 = cp[top +  1], C0 = cp[top +  2];
                v4f A1 = cp[top + 31], B1 = cp[top + 32], C1 = cp[top + 33];
                v4f A2 = cp[top + 62], B2 = cp[top + 63], C2 = cp[top + 64];
                // px0 (center B1; rows r0,r0+1,r0+2)
                pk4(q0[0], B1, A0); pk4(q0[1], B1, B0); pk4(q0[2], B1, C0);
                pk4(q0[3], B1, A1); pk4(q0[4], B1, C1);
                pk4(q0[5], B1, A2); pk4(s01,   B1, B2); pk4(q0[6], B1, C2);
                v4f A3 = cp[top + 93], B3 = cp[top + 94], C3 = cp[top + 95];
                // px1 (center B2; rows r0+1,r0+2,r0+3); (-1,0) = s01
                pk4(q1[0], B2, A1); pk4(q1[1], B2, C1);
                pk4(q1[2], B2, A2); pk4(q1[3], B2, C2);
                pk4(q1[4], B2, A3); pk4(q1[5], B2, B3); pk4(q1[6], B2, C3);
            }
        }

        if (t + 1 < NCHUNK) {
            writebuf((t + 1) & 1, h0, h1);   // hold set = chunk t+1
            BAR();
        }
    };

    // ---- chunk loop, statically unrolled x2 for ping-pong (rule #20)
    for (int tt = 0; tt < NCHUNK; tt += 2) {
        step(tt,     pvA0, pvA1, pvB0, pvB1);
        step(tt + 1, pvB0, pvB1, pvA0, pvA1);
    }

    // ---- publish norm partials + cross-half dot partials
    ssp[half][t8] = ss0;
    if (t8 < EXTRA) ssp[half][t8 + NT2] = ss1;
    if (is_p) {
        if (half == 1) {   // send px0 partials (order 00,01,02,10,12,20,21,22)
            float* d = exA[t8];
            d[0]=q0[0].x+q0[0].y; d[1]=q0[1].x+q0[1].y; d[2]=q0[2].x+q0[2].y;
            d[3]=q0[3].x+q0[3].y; d[4]=q0[4].x+q0[4].y; d[5]=q0[5].x+q0[5].y;
            d[6]=s01.x+s01.y;     d[7]=q0[6].x+q0[6].y;
        } else {           // send px1 partials
            float* d = exB[t8];
            d[0]=q1[0].x+q1[0].y; d[1]=s01.x+s01.y;     d[2]=q1[1].x+q1[1].y;
            d[3]=q1[2].x+q1[2].y; d[4]=q1[3].x+q1[3].y; d[5]=q1[4].x+q1[4].y;
            d[6]=q1[5].x+q1[5].y; d[7]=q1[6].x+q1[6].y;
        }
    }
    __syncthreads();
    if (tid < TILE_E)
        ssbuf[tid] = 1.0f / fmaxf(sqrtf(ssp[0][tid] + ssp[1][tid]), 1e-12f);
    __syncthreads();

    float lp = 0.0f;
    if (is_p) {
        auto epi = [&](const float* s8, int ciu, int gi) -> float {
            const float ssq = ssp[0][ciu] + ssp[1][ciu];
            const float invc = ssbuf[ciu] * INV_T;
            const float l00 = s8[0] * invc * ssbuf[ciu - TCOLS - 1];
            const float l01 = s8[1] * invc * ssbuf[ciu - TCOLS];
            const float l02 = s8[2] * invc * ssbuf[ciu - TCOLS + 1];
            const float l10 = s8[3] * invc * ssbuf[ciu - 1];
            const float l11 = ssq  * invc * ssbuf[ciu];
            const float l12 = s8[4] * invc * ssbuf[ciu + 1];
            const float l20 = s8[5] * invc * ssbuf[ciu + TCOLS - 1];
            const float l21 = s8[6] * invc * ssbuf[ciu + TCOLS];
            const float l22 = s8[7] * invc * ssbuf[ciu + TCOLS + 1];

            const int pix = gi * W_ + gj;
            float denom = 0.f, sumlog = 0.f;
            #pragma unroll
            for (int m = 0; m < N_; ++m) {
                int d0 = dirs[((m * 2 + 0) * H_ + gi) * W_ + gj];
                int d1 = dirs[((m * 2 + 1) * H_ + gi) * W_ + gj];
                float e0 = sel3(d1, l00, l01, l02);
                float e1 = sel3(d1, l10, l11, l12);
                float e2 = sel3(d1, l20, l21, l22);
                float lm = sel3(d0, e0, e1, e2);
                int labm = labels[m * HW + pix];
                int labn = labels[n * HW + (gi + d0) * W_ + (gj + d1)];
                bool msk = (labm == labn);
                float e = msk ? __expf(lm) : 0.f;
                denom += e;
                sumlog += msk ? lm : -INFINITY;
            }
            return 8.0f * __logf(denom + 1e-6f) - sumlog;
        };

        if (half == 0) {
            if (px0v) {   // own px0: combine with half1's exA
                float f[8];
                const float* e = exA[t8];
                f[0]=q0[0].x+q0[0].y+e[0]; f[1]=q0[1].x+q0[1].y+e[1];
                f[2]=q0[2].x+q0[2].y+e[2]; f[3]=q0[3].x+q0[3].y+e[3];
                f[4]=q0[4].x+q0[4].y+e[4]; f[5]=q0[5].x+q0[5].y+e[5];
                f[6]=s01.x+s01.y+e[6];     f[7]=q0[6].x+q0[6].y+e[7];
                lp = epi(f, (r0 + 1) * TCOLS + tx + 1, gy0 + r0);
            }
        } else {          // own px1: combine with half0's exB
            float f[8];
            const float* e = exB[t8];
            f[0]=q1[0].x+q1[0].y+e[0]; f[1]=s01.x+s01.y+e[1];
            f[2]=q1[1].x+q1[1].y+e[2]; f[3]=q1[2].x+q1[2].y+e[3];
            f[4]=q1[3].x+q1[3].y+e[4]; f[5]=q1[4].x+q1[4].y+e[5];
            f[6]=q1[5].x+q1[5].y+e[6]; f[7]=q1[6].x+q1[6].y+e[7];
            lp = epi(f, (r0 + 2) * TCOLS + tx + 1, gy0 + r0 + 1);
        }
    }

    // ---- block reduction (8 waves)
    #pragma unroll
    for (int off = 32; off > 0; off >>= 1) lp += __shfl_down(lp, off, 64);
    const int wave = tid >> 6, lane = tid & 63;
    if (lane == 0) red[wave] = lp;
    __syncthreads();
    if (tid == 0) {
        float tsum = 0.f;
        #pragma unroll
        for (int w = 0; w < NT / 64; ++w) tsum += red[w];
        if (use_partial) partial[bid] = (double)tsum;
        else atomicAdd(partial, (double)tsum);
    }
}

extern "C" __global__ void __launch_bounds__(256)
dcl_final(const double* __restrict__ partial, float* __restrict__ out, int nblk)
{
    const int tid = threadIdx.x;
    double s = 0.0;
    for (int i = tid; i < nblk; i += 256) s += partial[i];
    #pragma unroll
    for (int off = 32; off > 0; off >>= 1) s += __shfl_down(s, off, 64);
    __shared__ double red[4];
    const int lane = tid & 63, wv = tid >> 6;
    if (lane == 0) red[wv] = s;
    __syncthreads();
    if (tid == 0) out[0] = (float)((red[0] + red[1] + red[2] + red[3]) / TOTAL);
}

extern "C" void kernel_launch(void* const* d_in, const int* in_sizes, int n_in,
                              void* d_out, int out_size, void* d_ws, size_t ws_size,
                              hipStream_t stream) {
    const float* feat   = (const float*)d_in[0];
    const int*   labels = (const int*)d_in[1];
    const int*   dirs   = (const int*)d_in[2];
    double* acc = (double*)d_ws;
    float*  out = (float*)d_out;

    const int use_partial = (ws_size >= (size_t)NBLK * sizeof(double)) ? 1 : 0;
    if (!use_partial) hipMemsetAsync(acc, 0, sizeof(double), stream);
    dcl_main<<<dim3(NBLK), NT, 0, stream>>>(feat, labels, dirs, acc, use_partial);
    dcl_final<<<1, 256, 0, stream>>>(acc, out, use_partial ? NBLK : 1);
}

// Round 9
// 120.152 us; speedup vs baseline: 1.1549x; 1.0248x over previous
//
#include <hip/hip_runtime.h>
#include <math.h>

// DirectionalContrastiveLoss — N=8, C=192, H=W=112, T=0.1
//
// R14 = R7 revert (best measured: 119.2 us). Session conclusion: dcl_main
// is an HBM-stream-bound kernel running within ~5-10% of its traffic
// entitlement (102-120 MB @ ~6 TB/s ≈ 19-21 us floor; measured 22-23 us);
// total dur is dominated by 2x47us harness fills at 82% HBM peak.
// Attacks measured and falsified: occupancy (R8/R9), halo/XCD-L2 (R10),
// barrier-free wave-private tiles (R11), narrow-tile geometry (R12),
// counted-vmcnt + 2-deep prefetch (R13). Staging-segment width is the
// one live variable (64B=49us, 120B=25us, 232B=22us); R7 sits at 232B.
//
//  - NT=512, two 256-thread channel-halves (ch 0..95 / 96..191).
//  - tile 4x56 (+halo = 6x58): halo factor 1.55; grid (2,28,8)=448 blocks.
//  - LDS float4 groups; KCH=8 double-buffered (12 barriers).
//  - v_pk_fma_f32 accumulation; center self-dot from staged norm sums.

namespace {
constexpr int N_ = 8, C_ = 192, H_ = 112, W_ = 112;
constexpr int HW = H_ * W_;
constexpr int TH = 4;                  // pixel rows per block
constexpr int WS = 56;                 // pixel cols per block
constexpr int TROWS = TH + 2;          // 6
constexpr int TCOLS = WS + 2;          // 58
constexpr int TILE_E = TROWS * TCOLS;  // 348
constexpr int NT2 = 256;               // threads per channel-half
constexpr int NT = 2 * NT2;            // 512
constexpr int NPX = TH * WS;           // 224 compute threads per half
constexpr int EXTRA = TILE_E - NT2;    // 92 threads own a 2nd staging slot
constexpr int CHALF = C_ / 2;          // 96 channels per half
constexpr int KCH = 8;                 // channels per chunk (per half)
constexpr int GRP = KCH / 4;           // 2 float4 groups
constexpr int NCHUNK = CHALF / KCH;    // 12 chunks -> 12 barriers
constexpr int NBLK = (W_ / WS) * (H_ / TH) * N_;  // 2*28*8 = 448
constexpr float INV_T = 10.0f;
constexpr double TOTAL = (double)N_ * N_ * H_ * W_;  // 802816
}

typedef float v2f __attribute__((ext_vector_type(2)));
typedef float v4f __attribute__((ext_vector_type(4)));

__device__ __forceinline__ void pkfma(v2f& a, v2f x, v2f y) {
    asm("v_pk_fma_f32 %0, %1, %2, %0" : "+v"(a) : "v"(x), "v"(y));
}

__device__ __forceinline__ float sel3(int d, float a, float b, float c) {
    float r = (d < 0) ? a : b;
    return (d > 0) ? c : r;
}

extern "C" __global__ void __launch_bounds__(NT, 4)
dcl_main(const float* __restrict__ feat,
         const int* __restrict__ labels,
         const int* __restrict__ dirs,
         double* __restrict__ partial, int use_partial)
{
    __shared__ v4f   tiles[2][2][GRP][TILE_E];  // [half][dbuf][grp] = 44.5 KB
    __shared__ float ssp[2][TILE_E];            // per-half norm partials
    __shared__ float ssbuf[TILE_E];             // combined inv-norms
    __shared__ float scomb[NPX][9];             // half1 dot partials (pad->9)
    __shared__ float red[NT / 64];

    const int tid  = threadIdx.x;
    const int half = tid >> 8;          // channel half: 0 or 1
    const int t8   = tid & (NT2 - 1);   // index within half
    const int gx0 = blockIdx.x * WS;
    const int gy0 = blockIdx.y * TH;
    const int n   = blockIdx.z;

    // ---- staging slot -> clamped global offset
    int gofs0, gofs1 = 0;
    {
        int r = t8 / TCOLS, c = t8 - r * TCOLS;
        gofs0 = min(max(gy0 + r - 1, 0), H_ - 1) * W_ + min(max(gx0 + c - 1, 0), W_ - 1);
        if (t8 < EXTRA) {
            int t2 = t8 + NT2;
            r = t2 / TCOLS; c = t2 - r * TCOLS;
            gofs1 = min(max(gy0 + r - 1, 0), H_ - 1) * W_ + min(max(gx0 + c - 1, 0), W_ - 1);
        }
    }

    const bool is_px = (t8 < NPX);
    const int ty = t8 / WS;               // 0..3
    const int tx = t8 - ty * WS;          // 0..55
    const int gi = gy0 + ty;
    const int gj = gx0 + tx;
    const int ci = (ty + 1) * TCOLS + (tx + 1);

    const float* __restrict__ plane =
        feat + ((size_t)n * C_ + (size_t)half * CHALF) * HW;

    float ss0 = 0.0f, ss1 = 0.0f;

    // ---- prologue: stage chunk 0 into buffer 0
    {
        #pragma unroll
        for (int g = 0; g < GRP; ++g) {
            float a0 = plane[(size_t)(4 * g + 0) * HW + gofs0];
            float a1 = plane[(size_t)(4 * g + 1) * HW + gofs0];
            float a2 = plane[(size_t)(4 * g + 2) * HW + gofs0];
            float a3 = plane[(size_t)(4 * g + 3) * HW + gofs0];
            ss0 += a0 * a0 + a1 * a1 + a2 * a2 + a3 * a3;
            v4f v = {a0, a1, a2, a3};
            tiles[half][0][g][t8] = v;
        }
        if (t8 < EXTRA) {
            #pragma unroll
            for (int g = 0; g < GRP; ++g) {
                float a0 = plane[(size_t)(4 * g + 0) * HW + gofs1];
                float a1 = plane[(size_t)(4 * g + 1) * HW + gofs1];
                float a2 = plane[(size_t)(4 * g + 2) * HW + gofs1];
                float a3 = plane[(size_t)(4 * g + 3) * HW + gofs1];
                ss1 += a0 * a0 + a1 * a1 + a2 * a2 + a3 * a3;
                v4f v = {a0, a1, a2, a3};
                tiles[half][0][g][t8 + NT2] = v;
            }
        }
    }
    __syncthreads();

    v2f s2[9];
    const v2f zero2 = {0.0f, 0.0f};
    #pragma unroll
    for (int d = 0; d < 9; ++d) s2[d] = zero2;

    // ---- chunk loop: 1 barrier per 8 channels per half, double-buffered
    for (int t = 0; t < NCHUNK; ++t) {
        float pv0[KCH], pv1[KCH];
        const bool more = (t + 1 < NCHUNK);
        if (more) {
            const float* p = plane + (size_t)(t + 1) * KCH * HW;
            #pragma unroll
            for (int k = 0; k < KCH; ++k) pv0[k] = p[(size_t)k * HW + gofs0];
            if (t8 < EXTRA) {
                #pragma unroll
                for (int k = 0; k < KCH; ++k) pv1[k] = p[(size_t)k * HW + gofs1];
            }
        }

        if (is_px) {
            #pragma unroll
            for (int g = 0; g < GRP; ++g) {
                const v4f* __restrict__ cp = tiles[half][t & 1][g];
                v4f fc  = cp[ci];
                v4f n00 = cp[ci - TCOLS - 1];
                v4f n01 = cp[ci - TCOLS];
                v4f n02 = cp[ci - TCOLS + 1];
                v4f n10 = cp[ci - 1];
                v4f n12 = cp[ci + 1];
                v4f n20 = cp[ci + TCOLS - 1];
                v4f n21 = cp[ci + TCOLS];
                v4f n22 = cp[ci + TCOLS + 1];
                pkfma(s2[0], fc.lo, n00.lo); pkfma(s2[0], fc.hi, n00.hi);
                pkfma(s2[1], fc.lo, n01.lo); pkfma(s2[1], fc.hi, n01.hi);
                pkfma(s2[2], fc.lo, n02.lo); pkfma(s2[2], fc.hi, n02.hi);
                pkfma(s2[3], fc.lo, n10.lo); pkfma(s2[3], fc.hi, n10.hi);
                pkfma(s2[5], fc.lo, n12.lo); pkfma(s2[5], fc.hi, n12.hi);
                pkfma(s2[6], fc.lo, n20.lo); pkfma(s2[6], fc.hi, n20.hi);
                pkfma(s2[7], fc.lo, n21.lo); pkfma(s2[7], fc.hi, n21.hi);
                pkfma(s2[8], fc.lo, n22.lo); pkfma(s2[8], fc.hi, n22.hi);
            }
        }

        if (more) {
            const int nb = (t + 1) & 1;
            #pragma unroll
            for (int g = 0; g < GRP; ++g) {
                float a0 = pv0[2 * 4 * g / 4 + 0], a1 = pv0[4 * g + 1];
                float a2 = pv0[4 * g + 2], a3 = pv0[4 * g + 3];
                a0 = pv0[4 * g];
                ss0 += a0 * a0 + a1 * a1 + a2 * a2 + a3 * a3;
                v4f v = {a0, a1, a2, a3};
                tiles[half][nb][g][t8] = v;
            }
            if (t8 < EXTRA) {
                #pragma unroll
                for (int g = 0; g < GRP; ++g) {
                    float a0 = pv1[4 * g], a1 = pv1[4 * g + 1];
                    float a2 = pv1[4 * g + 2], a3 = pv1[4 * g + 3];
                    ss1 += a0 * a0 + a1 * a1 + a2 * a2 + a3 * a3;
                    v4f v = {a0, a1, a2, a3};
                    tiles[half][nb][g][t8 + NT2] = v;
                }
            }
            __syncthreads();
        }
    }

    // ---- publish per-half norm partials + half1's dot partials
    ssp[half][t8] = ss0;
    if (t8 < EXTRA) ssp[half][t8 + NT2] = ss1;
    if (half == 1 && is_px) {
        scomb[t8][0] = s2[0].x + s2[0].y;
        scomb[t8][1] = s2[1].x + s2[1].y;
        scomb[t8][2] = s2[2].x + s2[2].y;
        scomb[t8][3] = s2[3].x + s2[3].y;
        scomb[t8][4] = s2[5].x + s2[5].y;
        scomb[t8][5] = s2[6].x + s2[6].y;
        scomb[t8][6] = s2[7].x + s2[7].y;
        scomb[t8][7] = s2[8].x + s2[8].y;
    }
    __syncthreads();
    if (tid < TILE_E)
        ssbuf[tid] = 1.0f / fmaxf(sqrtf(ssp[0][tid] + ssp[1][tid]), 1e-12f);
    __syncthreads();

    float lp = 0.0f;
    if (half == 0 && is_px) {
        const float sA = s2[0].x + s2[0].y + scomb[t8][0];
        const float sB = s2[1].x + s2[1].y + scomb[t8][1];
        const float sC = s2[2].x + s2[2].y + scomb[t8][2];
        const float sD = s2[3].x + s2[3].y + scomb[t8][3];
        const float sE = s2[5].x + s2[5].y + scomb[t8][4];
        const float sF = s2[6].x + s2[6].y + scomb[t8][5];
        const float sG = s2[7].x + s2[7].y + scomb[t8][6];
        const float sH = s2[8].x + s2[8].y + scomb[t8][7];
        const float ssq = ssp[0][ci] + ssp[1][ci];   // center self-dot

        const float invc = ssbuf[ci] * INV_T;
        const float l00 = sA  * invc * ssbuf[ci - TCOLS - 1];
        const float l01 = sB  * invc * ssbuf[ci - TCOLS];
        const float l02 = sC  * invc * ssbuf[ci - TCOLS + 1];
        const float l10 = sD  * invc * ssbuf[ci - 1];
        const float l11 = ssq * invc * ssbuf[ci];
        const float l12 = sE  * invc * ssbuf[ci + 1];
        const float l20 = sF  * invc * ssbuf[ci + TCOLS - 1];
        const float l21 = sG  * invc * ssbuf[ci + TCOLS];
        const float l22 = sH  * invc * ssbuf[ci + TCOLS + 1];

        const int pix = gi * W_ + gj;
        float denom = 0.f, sumlog = 0.f;
        #pragma unroll
        for (int m = 0; m < N_; ++m) {
            int d0 = dirs[((m * 2 + 0) * H_ + gi) * W_ + gj];
            int d1 = dirs[((m * 2 + 1) * H_ + gi) * W_ + gj];
            float q0 = sel3(d1, l00, l01, l02);
            float q1 = sel3(d1, l10, l11, l12);
            float q2 = sel3(d1, l20, l21, l22);
            float lm = sel3(d0, q0, q1, q2);
            int labm = labels[m * HW + pix];
            int labn = labels[n * HW + (gi + d0) * W_ + (gj + d1)];
            bool msk = (labm == labn);
            float e = msk ? __expf(lm) : 0.f;
            denom += e;
            sumlog += msk ? lm : -INFINITY;
        }
        lp = 8.0f * __logf(denom + 1e-6f) - sumlog;
    }

    // ---- block reduction (8 waves)
    #pragma unroll
    for (int off = 32; off > 0; off >>= 1) lp += __shfl_down(lp, off, 64);
    const int wave = tid >> 6, lane = tid & 63;
    if (lane == 0) red[wave] = lp;
    __syncthreads();
    if (tid == 0) {
        float tsum = 0.f;
        #pragma unroll
        for (int w = 0; w < NT / 64; ++w) tsum += red[w];
        const int bid = (blockIdx.z * gridDim.y + blockIdx.y) * gridDim.x + blockIdx.x;
        if (use_partial) partial[bid] = (double)tsum;
        else atomicAdd(partial, (double)tsum);
    }
}

extern "C" __global__ void __launch_bounds__(256)
dcl_final(const double* __restrict__ partial, float* __restrict__ out, int nblk)
{
    const int tid = threadIdx.x;
    double s = 0.0;
    for (int i = tid; i < nblk; i += 256) s += partial[i];
    #pragma unroll
    for (int off = 32; off > 0; off >>= 1) s += __shfl_down(s, off, 64);
    __shared__ double red[4];
    const int lane = tid & 63, wv = tid >> 6;
    if (lane == 0) red[wv] = s;
    __syncthreads();
    if (tid == 0) out[0] = (float)((red[0] + red[1] + red[2] + red[3]) / TOTAL);
}

extern "C" void kernel_launch(void* const* d_in, const int* in_sizes, int n_in,
                              void* d_out, int out_size, void* d_ws, size_t ws_size,
                              hipStream_t stream) {
    const float* feat   = (const float*)d_in[0];
    const int*   labels = (const int*)d_in[1];
    const int*   dirs   = (const int*)d_in[2];
    double* acc = (double*)d_ws;
    float*  out = (float*)d_out;

    const int use_partial = (ws_size >= (size_t)NBLK * sizeof(double)) ? 1 : 0;
    if (!use_partial) hipMemsetAsync(acc, 0, sizeof(double), stream);
    dim3 grid(W_ / WS, H_ / TH, N_);      // (2, 28, 8) = 448 blocks
    dcl_main<<<grid, NT, 0, stream>>>(feat, labels, dirs, acc, use_partial);
    dcl_final<<<1, 256, 0, stream>>>(acc, out, use_partial ? NBLK : 1);
}